// Round 1
// baseline (1699.916 us; speedup 1.0000x reference)
//
#include <hip/hip_runtime.h>

#define B_  16
#define S_  1024
#define L_  512
#define D_  1024
#define H_  8
#define DH_ 128
#define WD_ 256
#define KP_ (D_ + WD_)

#define BM 64
#define BN 64
#define BK 16

#define MODE_PLAIN 0
#define MODE_Q     1
#define MODE_P     2

// Y[m,n] = (sum_k A[m,k]*W[n,k] + bias[n]) * scale
// MODE_Q: A row m is enc[b, to_sem[b,l], :] (gathered), b = m/512
// MODE_P: A[m,k] = k<1024 ? semvec[m,k] : type_emb[tidx[m], k-1024]; also writes Y2 (out2)
template <int MODE>
__global__ __launch_bounds__(256) void gemm_k(
    const float* __restrict__ A, const float* __restrict__ W,
    const float* __restrict__ bias, float* __restrict__ Y,
    int M, int N, int K,
    const float* __restrict__ enc, const int* __restrict__ gidx,
    const float* __restrict__ temb, const int* __restrict__ tidx,
    float scale, float* __restrict__ Y2)
{
    __shared__ float As[BK][BM + 4];
    __shared__ float Bs[BK][BN + 4];
    __shared__ int rowsrc[BM];

    const int tid = threadIdx.x;
    const int bn0 = blockIdx.x * BN;
    const int bm0 = blockIdx.y * BM;

    if (MODE == MODE_Q) { if (tid < BM) rowsrc[tid] = gidx[bm0 + tid]; }
    if (MODE == MODE_P) { if (tid < BM) rowsrc[tid] = tidx[bm0 + tid]; }
    __syncthreads();

    const int arow = tid >> 2;   // 0..63
    const int ac4  = tid & 3;    // 0..3 (float4 column within 16-wide K tile)
    const int ty = tid >> 4, tx = tid & 15;

    float acc[4][4] = {};

    for (int k0 = 0; k0 < K; k0 += BK) {
        float4 av;
        if (MODE == MODE_PLAIN) {
            av = *(const float4*)(A + (size_t)(bm0 + arow) * K + k0 + ac4 * 4);
        } else if (MODE == MODE_Q) {
            int b = (bm0 + arow) >> 9;
            av = *(const float4*)(enc + ((size_t)b * S_ + rowsrc[arow]) * D_ + k0 + ac4 * 4);
        } else { // MODE_P
            if (k0 < D_)
                av = *(const float4*)(A + (size_t)(bm0 + arow) * D_ + k0 + ac4 * 4);
            else
                av = *(const float4*)(temb + (size_t)rowsrc[arow] * WD_ + (k0 - D_) + ac4 * 4);
        }
        float4 bv = *(const float4*)(W + (size_t)(bn0 + arow) * K + k0 + ac4 * 4);

        As[ac4 * 4 + 0][arow] = av.x;
        As[ac4 * 4 + 1][arow] = av.y;
        As[ac4 * 4 + 2][arow] = av.z;
        As[ac4 * 4 + 3][arow] = av.w;
        Bs[ac4 * 4 + 0][arow] = bv.x;
        Bs[ac4 * 4 + 1][arow] = bv.y;
        Bs[ac4 * 4 + 2][arow] = bv.z;
        Bs[ac4 * 4 + 3][arow] = bv.w;
        __syncthreads();

        #pragma unroll
        for (int kk = 0; kk < BK; ++kk) {
            float4 a = *(const float4*)&As[kk][ty * 4];
            float4 b = *(const float4*)&Bs[kk][tx * 4];
            float ar[4] = {a.x, a.y, a.z, a.w};
            float br[4] = {b.x, b.y, b.z, b.w};
            #pragma unroll
            for (int i = 0; i < 4; ++i)
                #pragma unroll
                for (int j = 0; j < 4; ++j)
                    acc[i][j] = fmaf(ar[i], br[j], acc[i][j]);
        }
        __syncthreads();
    }

    #pragma unroll
    for (int i = 0; i < 4; ++i) {
        const int m = bm0 + ty * 4 + i;
        float4 o;
        float* op = &o.x;
        #pragma unroll
        for (int j = 0; j < 4; ++j) {
            const int n = bn0 + tx * 4 + j;
            op[j] = (acc[i][j] + bias[n]) * scale;
        }
        *(float4*)(Y + (size_t)m * N + bn0 + tx * 4) = o;
        if (MODE == MODE_P) {
            const int bb = m >> 9, ll = m & 511;
            *(float4*)(Y2 + ((size_t)bb * (L_ + 1) + ll + 1) * D_ + bn0 + tx * 4) = o;
        }
    }
}

// Sparse masked attention. One block per (b,l). qctx holds q rows on input,
// ctx rows on output (in-place per row). allow(b,l,s) = sem_syn[b,s]==l+1 || s==to_sem[b,l].
__global__ __launch_bounds__(256) void attn_k(
    const float* __restrict__ k, const float* __restrict__ v,
    const int* __restrict__ sem_syn, const int* __restrict__ to_sem,
    float* __restrict__ qctx)
{
    __shared__ int   list[S_];
    __shared__ float sc[H_][S_];
    __shared__ int   pcnt[256];

    const int bl  = blockIdx.x;
    const int b   = bl >> 9;
    const int l   = bl & 511;
    const int tid = threadIdx.x;

    // each thread owns dims [tid*4, tid*4+4); head g = tid>>5
    const float4 qv = *(const float4*)(qctx + (size_t)bl * D_ + tid * 4);

    // --- deterministic mask compaction (prefix-sum, list sorted by s) ---
    const int tosem = to_sem[bl];
    bool al[4];
    int  cl = 0;
    #pragma unroll
    for (int j = 0; j < 4; ++j) {
        const int s = tid * 4 + j;
        const int a = sem_syn[b * S_ + s];
        al[j] = (a == l + 1) || (s == tosem);
        cl += al[j] ? 1 : 0;
    }
    pcnt[tid] = cl;
    __syncthreads();
    for (int off = 1; off < 256; off <<= 1) {
        const int x = (tid >= off) ? pcnt[tid - off] : 0;
        __syncthreads();
        pcnt[tid] += x;
        __syncthreads();
    }
    int pos = pcnt[tid] - cl;
    #pragma unroll
    for (int j = 0; j < 4; ++j)
        if (al[j]) list[pos++] = tid * 4 + j;
    const int n = pcnt[255];   // >= 1 always (self position)
    __syncthreads();

    // --- scores: sc[h][i] = q[b,l,h,:] . k[b,s_i,h,:] ---
    const int g = tid >> 5;
    const int lane = tid & 31;
    for (int i = 0; i < n; ++i) {
        const float* krow = k + ((size_t)b * S_ + list[i]) * D_;
        const float4 kv = *(const float4*)(krow + tid * 4);
        float p = kv.x * qv.x + kv.y * qv.y + kv.z * qv.z + kv.w * qv.w;
        #pragma unroll
        for (int off = 16; off > 0; off >>= 1) p += __shfl_down(p, off, 32);
        if (lane == 0) sc[g][i] = p;
    }
    __syncthreads();

    // --- softmax over the allowed set, per head (group of 32 lanes) ---
    float mx = -3.0e38f;
    for (int i = lane; i < n; i += 32) mx = fmaxf(mx, sc[g][i]);
    #pragma unroll
    for (int off = 16; off > 0; off >>= 1) mx = fmaxf(mx, __shfl_xor(mx, off, 32));
    float sum = 0.f;
    for (int i = lane; i < n; i += 32) {
        const float e = expf(sc[g][i] - mx);
        sc[g][i] = e;
        sum += e;
    }
    #pragma unroll
    for (int off = 16; off > 0; off >>= 1) sum += __shfl_xor(sum, off, 32);
    const float inv = 1.0f / sum;
    __syncthreads();

    // --- ctx = sum_i p_i * v[b,s_i,:] ---
    float4 a4 = make_float4(0.f, 0.f, 0.f, 0.f);
    for (int i = 0; i < n; ++i) {
        const float w = sc[g][i] * inv;
        const float* vrow = v + ((size_t)b * S_ + list[i]) * D_;
        const float4 vv = *(const float4*)(vrow + tid * 4);
        a4.x = fmaf(w, vv.x, a4.x);
        a4.y = fmaf(w, vv.y, a4.y);
        a4.z = fmaf(w, vv.z, a4.z);
        a4.w = fmaf(w, vv.w, a4.w);
    }
    *(float4*)(qctx + (size_t)bl * D_ + tid * 4) = a4;
}

__global__ __launch_bounds__(256) void root_k(
    const float* __restrict__ broot, float* __restrict__ out2)
{
    const int i = blockIdx.x * 256 + threadIdx.x;   // B*D threads
    const int b = i >> 10, d = i & 1023;
    out2[(size_t)b * (L_ + 1) * D_ + d] = broot[d];
}

extern "C" void kernel_launch(void* const* d_in, const int* in_sizes, int n_in,
                              void* d_out, int out_size, void* d_ws, size_t ws_size,
                              hipStream_t stream)
{
    const float* enc    = (const float*)d_in[0];
    const int*   to_sem = (const int*)  d_in[1];
    const int*   tstype = (const int*)  d_in[2];
    const int*   semsyn = (const int*)  d_in[3];
    const float* wq = (const float*)d_in[4];
    const float* bq = (const float*)d_in[5];
    const float* wk = (const float*)d_in[6];
    const float* bk = (const float*)d_in[7];
    const float* wv = (const float*)d_in[8];
    const float* bv = (const float*)d_in[9];
    const float* wo = (const float*)d_in[10];
    const float* bo = (const float*)d_in[11];
    const float* temb  = (const float*)d_in[12];
    const float* wproj = (const float*)d_in[13];
    const float* bproj = (const float*)d_in[14];
    const float* broot = (const float*)d_in[15];

    float* out1 = (float*)d_out;                       // [B,L,D]
    float* out2 = out1 + (size_t)B_ * L_ * D_;         // [B,L+1,D]

    float* kbuf = (float*)d_ws;                        // [B,S,D]  64 MiB
    float* qbuf = kbuf + (size_t)B_ * S_ * D_;         // [B,L,D]  32 MiB (q, then ctx in-place)
    float* vbuf = out1;                                // v scratch lives in d_out (dead before final proj)

    const float qscale = 0.08838834764831845f;         // DH^-0.5
    dim3 blk(256);

    // k = enc @ wk^T + bk
    gemm_k<MODE_PLAIN><<<dim3(D_ / BN, (B_ * S_) / BM), blk, 0, stream>>>(
        enc, wk, bk, kbuf, B_ * S_, D_, D_,
        nullptr, nullptr, nullptr, nullptr, 1.0f, nullptr);
    // v = enc @ wv^T + bv
    gemm_k<MODE_PLAIN><<<dim3(D_ / BN, (B_ * S_) / BM), blk, 0, stream>>>(
        enc, wv, bv, vbuf, B_ * S_, D_, D_,
        nullptr, nullptr, nullptr, nullptr, 1.0f, nullptr);
    // q = (gather(enc, to_sem) @ wq^T + bq) * scale
    gemm_k<MODE_Q><<<dim3(D_ / BN, (B_ * L_) / BM), blk, 0, stream>>>(
        nullptr, wq, bq, qbuf, B_ * L_, D_, D_,
        enc, to_sem, nullptr, nullptr, qscale, nullptr);
    // sparse masked attention: ctx overwrites q rows
    attn_k<<<dim3(B_ * L_), blk, 0, stream>>>(kbuf, vbuf, semsyn, to_sem, qbuf);
    // semvec = ctx @ wo^T + bo   (into kbuf; k is dead)
    gemm_k<MODE_PLAIN><<<dim3(D_ / BN, (B_ * L_) / BM), blk, 0, stream>>>(
        qbuf, wo, bo, kbuf, B_ * L_, D_, D_,
        nullptr, nullptr, nullptr, nullptr, 1.0f, nullptr);
    // embedding = [semvec | type_emb[tstype]] @ wproj^T + bproj -> out1 and out2 rows 1..L
    gemm_k<MODE_P><<<dim3(D_ / BN, (B_ * L_) / BM), blk, 0, stream>>>(
        kbuf, wproj, bproj, out1, B_ * L_, D_, KP_,
        nullptr, nullptr, temb, tstype, 1.0f, out2);
    // out2 row 0 per batch = bias_root
    root_k<<<dim3((B_ * D_) / 256), blk, 0, stream>>>(broot, out2);
}

// Round 2
// 285.089 us; speedup vs baseline: 5.9628x; 5.9628x over previous
//
#include <hip/hip_runtime.h>

typedef unsigned short u16;
typedef unsigned int   u32;
typedef __bf16 bf16x8 __attribute__((ext_vector_type(8)));
typedef float  f32x4  __attribute__((ext_vector_type(4)));

#define B_  16
#define S_  1024
#define L_  512
#define D_  1024
#define H_  8
#define WD_ 256
#define KP_ (D_ + WD_)

#define BM 128
#define BN 128
#define BK 32

__device__ __forceinline__ u16 f2bf(float f) {
    u32 u = __float_as_uint(f);
    return (u16)((u + 0x7FFFu + ((u >> 16) & 1u)) >> 16);
}
__device__ __forceinline__ float bf2f(u16 h) {
    return __uint_as_float(((u32)h) << 16);
}

__device__ __forceinline__ void gload16(const void* g, void* l) {
    __builtin_amdgcn_global_load_lds(
        (const __attribute__((address_space(1))) u32*)(unsigned long long)(g),
        (__attribute__((address_space(3))) u32*)(unsigned long long)(l),
        16, 0, 0);
}

// fp32 -> bf16 plane conversion, 4 elems/thread
__global__ __launch_bounds__(256) void conv_k(const float* __restrict__ x,
                                              u16* __restrict__ y, int n) {
    const int i = (blockIdx.x * 256 + threadIdx.x) * 4;
    if (i < n) {
        const float4 v = *(const float4*)(x + i);
        ushort4 o;
        o.x = f2bf(v.x); o.y = f2bf(v.y); o.z = f2bf(v.z); o.w = f2bf(v.w);
        *(ushort4*)(y + i) = o;
    }
}

#define AM_PLAIN  0
#define AM_GATHER 1
#define AM_CONCAT 2
#define OM_BF16   0
#define OM_FINAL  1

// Y = (A @ W^T + bias) * scale, A/W bf16, accum fp32, N fixed = 1024.
// AM_GATHER: A row m = aux[enc_bf][(m>>9)*S + gidx[m]] ; AM_CONCAT: k>=1024 from aux[temb_bf][gidx[m]]
// OM_BF16: write bf16 to Ybf ; OM_FINAL: write fp32 to Yf and Y2 (rows +1)
template <int AMODE, int OMODE>
__global__ __launch_bounds__(256) void mm_k(
    const u16* __restrict__ A, const u16* __restrict__ W,
    const float* __restrict__ bias,
    u16* __restrict__ Ybf, float* __restrict__ Yf, float* __restrict__ Y2,
    int M, int K,
    const int* __restrict__ gidx, const u16* __restrict__ aux, float scale)
{
    constexpr int N = 1024;
    __shared__ alignas(16) u16 As[BM * BK];
    __shared__ alignas(16) u16 Bs[BN * BK];

    const int tid  = threadIdx.x;
    const int wid  = tid >> 6;
    const int lane = tid & 63;

    // XCD-chunked swizzle (nwg % 8 == 0 always here); 8 N-tiles (N=1024/BN)
    const int nwg = gridDim.x;
    const int bid = blockIdx.x;
    const int e   = (bid & 7) * (nwg >> 3) + (bid >> 3);
    const int bm0 = (e >> 3) * BM;
    const int bn0 = (e & 7) * BN;

    // staging geometry: wave w stages A chunks {2w,2w+1} and B chunks {2w,2w+1}
    const int srow = lane >> 2;                              // row within 16-row chunk
    const int kcs  = ((lane & 3) ^ ((lane >> 2) & 3)) * 8;   // XOR-swizzled source k-chunk
    const int rA0  = 32 * wid + srow;
    const int rA1  = rA0 + 16;

    long gr0, gr1;
    if (AMODE == AM_PLAIN) {
        gr0 = (long)(bm0 + rA0) * K;
        gr1 = (long)(bm0 + rA1) * K;
    } else if (AMODE == AM_GATHER) {
        const int m0i = bm0 + rA0, m1i = bm0 + rA1;
        gr0 = ((long)(m0i >> 9) * S_ + gidx[m0i]) * D_;
        gr1 = ((long)(m1i >> 9) * S_ + gidx[m1i]) * D_;
    } else {
        gr0 = (long)(bm0 + rA0) * D_;
        gr1 = (long)(bm0 + rA1) * D_;
    }
    long tr0 = 0, tr1 = 0;
    if (AMODE == AM_CONCAT) {
        tr0 = (long)gidx[bm0 + rA0] * WD_;
        tr1 = (long)gidx[bm0 + rA1] * WD_;
    }
    const long wr0 = (long)(bn0 + rA0) * K;
    const long wr1 = (long)(bn0 + rA1) * K;

    u16* aB0 = As + (2 * wid) * 512;
    u16* aB1 = As + (2 * wid + 1) * 512;
    u16* bB0 = Bs + (2 * wid) * 512;
    u16* bB1 = Bs + (2 * wid + 1) * 512;

    f32x4 acc[4][4] = {};

    const int moff = (wid >> 1) * 64;
    const int noff = (wid & 1) * 64;
    const int l15  = lane & 15;
    const int lk   = lane >> 4;
    const int rdk  = (lk ^ (l15 & 3)) * 8;   // XOR-swizzled read k-chunk

    for (int k0 = 0; k0 < K; k0 += BK) {
        const u16 *a0, *a1;
        if (AMODE == AM_CONCAT && k0 >= D_) {
            a0 = aux + tr0 + (k0 - D_) + kcs;
            a1 = aux + tr1 + (k0 - D_) + kcs;
        } else if (AMODE == AM_GATHER) {
            a0 = aux + gr0 + k0 + kcs;
            a1 = aux + gr1 + k0 + kcs;
        } else {
            a0 = A + gr0 + k0 + kcs;
            a1 = A + gr1 + k0 + kcs;
        }
        gload16(a0, aB0);
        gload16(a1, aB1);
        gload16(W + wr0 + k0 + kcs, bB0);
        gload16(W + wr1 + k0 + kcs, bB1);
        __syncthreads();

        bf16x8 af[4], bfr[4];
        #pragma unroll
        for (int i = 0; i < 4; ++i)
            af[i] = *(const bf16x8*)(As + (moff + i * 16 + l15) * 32 + rdk);
        #pragma unroll
        for (int j = 0; j < 4; ++j)
            bfr[j] = *(const bf16x8*)(Bs + (noff + j * 16 + l15) * 32 + rdk);
        #pragma unroll
        for (int i = 0; i < 4; ++i)
            #pragma unroll
            for (int j = 0; j < 4; ++j)
                acc[i][j] = __builtin_amdgcn_mfma_f32_16x16x32_bf16(af[i], bfr[j], acc[i][j], 0, 0, 0);
        __syncthreads();
    }

    #pragma unroll
    for (int j = 0; j < 4; ++j) {
        const int col = bn0 + noff + j * 16 + l15;
        const float bj = bias[col];
        #pragma unroll
        for (int i = 0; i < 4; ++i) {
            const int mrow = bm0 + moff + i * 16 + lk * 4;
            #pragma unroll
            for (int r = 0; r < 4; ++r) {
                const float val = (acc[i][j][r] + bj) * scale;
                const long m = mrow + r;
                if (OMODE == OM_BF16) {
                    Ybf[m * N + col] = f2bf(val);
                } else {
                    Yf[m * (long)N + col] = val;
                    const long bb = m >> 9, ll = m & 511;
                    Y2[((bb * (L_ + 1)) + ll + 1) * (long)D_ + col] = val;
                }
            }
        }
    }
}

// Sparse masked attention, bf16 operands, fp32 math. One block per (b,l).
// qctx: q rows bf16 in, ctx rows bf16 out (in-place).
__global__ __launch_bounds__(256) void attn_k(
    const u16* __restrict__ kb, const u16* __restrict__ vb,
    const int* __restrict__ sem_syn, const int* __restrict__ to_sem,
    u16* __restrict__ qctx)
{
    __shared__ int   list[S_];
    __shared__ float sc[H_][S_];
    __shared__ int   pcnt[256];

    const int bl  = blockIdx.x;
    const int b   = bl >> 9;
    const int l   = bl & 511;
    const int tid = threadIdx.x;

    const ushort4 qu = *(const ushort4*)(qctx + (size_t)bl * D_ + tid * 4);
    const float4 qv = make_float4(bf2f(qu.x), bf2f(qu.y), bf2f(qu.z), bf2f(qu.w));

    // deterministic mask compaction
    const int tosem = to_sem[bl];
    bool al[4];
    int  cl = 0;
    #pragma unroll
    for (int j = 0; j < 4; ++j) {
        const int s = tid * 4 + j;
        const int a = sem_syn[b * S_ + s];
        al[j] = (a == l + 1) || (s == tosem);
        cl += al[j] ? 1 : 0;
    }
    pcnt[tid] = cl;
    __syncthreads();
    for (int off = 1; off < 256; off <<= 1) {
        const int x = (tid >= off) ? pcnt[tid - off] : 0;
        __syncthreads();
        pcnt[tid] += x;
        __syncthreads();
    }
    int pos = pcnt[tid] - cl;
    #pragma unroll
    for (int j = 0; j < 4; ++j)
        if (al[j]) list[pos++] = tid * 4 + j;
    const int n = pcnt[255];
    __syncthreads();

    const int g = tid >> 5;
    const int lane = tid & 31;
    for (int i = 0; i < n; ++i) {
        const u16* krow = kb + ((size_t)b * S_ + list[i]) * D_;
        const ushort4 ku = *(const ushort4*)(krow + tid * 4);
        float p = bf2f(ku.x) * qv.x + bf2f(ku.y) * qv.y + bf2f(ku.z) * qv.z + bf2f(ku.w) * qv.w;
        #pragma unroll
        for (int off = 16; off > 0; off >>= 1) p += __shfl_down(p, off, 32);
        if (lane == 0) sc[g][i] = p;
    }
    __syncthreads();

    float mx = -3.0e38f;
    for (int i = lane; i < n; i += 32) mx = fmaxf(mx, sc[g][i]);
    #pragma unroll
    for (int off = 16; off > 0; off >>= 1) mx = fmaxf(mx, __shfl_xor(mx, off, 32));
    float sum = 0.f;
    for (int i = lane; i < n; i += 32) {
        const float e = expf(sc[g][i] - mx);
        sc[g][i] = e;
        sum += e;
    }
    #pragma unroll
    for (int off = 16; off > 0; off >>= 1) sum += __shfl_xor(sum, off, 32);
    const float inv = 1.0f / sum;
    __syncthreads();

    float4 a4 = make_float4(0.f, 0.f, 0.f, 0.f);
    for (int i = 0; i < n; ++i) {
        const float w = sc[g][i] * inv;
        const u16* vrow = vb + ((size_t)b * S_ + list[i]) * D_;
        const ushort4 vu = *(const ushort4*)(vrow + tid * 4);
        a4.x = fmaf(w, bf2f(vu.x), a4.x);
        a4.y = fmaf(w, bf2f(vu.y), a4.y);
        a4.z = fmaf(w, bf2f(vu.z), a4.z);
        a4.w = fmaf(w, bf2f(vu.w), a4.w);
    }
    ushort4 o;
    o.x = f2bf(a4.x); o.y = f2bf(a4.y); o.z = f2bf(a4.z); o.w = f2bf(a4.w);
    *(ushort4*)(qctx + (size_t)bl * D_ + tid * 4) = o;
}

__global__ __launch_bounds__(256) void root_k(
    const float* __restrict__ broot, float* __restrict__ out2)
{
    const int i = blockIdx.x * 256 + threadIdx.x;
    const int b = i >> 10, d = i & 1023;
    out2[(size_t)b * (L_ + 1) * D_ + d] = broot[d];
}

extern "C" void kernel_launch(void* const* d_in, const int* in_sizes, int n_in,
                              void* d_out, int out_size, void* d_ws, size_t ws_size,
                              hipStream_t stream)
{
    const float* enc    = (const float*)d_in[0];
    const int*   to_sem = (const int*)  d_in[1];
    const int*   tstype = (const int*)  d_in[2];
    const int*   semsyn = (const int*)  d_in[3];
    const float* wq = (const float*)d_in[4];
    const float* bq = (const float*)d_in[5];
    const float* wk = (const float*)d_in[6];
    const float* bk = (const float*)d_in[7];
    const float* wv = (const float*)d_in[8];
    const float* bv = (const float*)d_in[9];
    const float* wo = (const float*)d_in[10];
    const float* bo = (const float*)d_in[11];
    const float* temb  = (const float*)d_in[12];
    const float* wproj = (const float*)d_in[13];
    const float* bproj = (const float*)d_in[14];
    const float* broot = (const float*)d_in[15];

    float* out1 = (float*)d_out;                     // [B,L,D] fp32 final
    float* out2 = out1 + (size_t)B_ * L_ * D_;       // [B,L+1,D] fp32 final

    unsigned char* ws = (unsigned char*)d_ws;
    u16* enc_bf = (u16*)ws;                              // 32 MiB
    u16* k_bf   = (u16*)(ws + (32ull << 20));            // 32 MiB
    u16* q_bf   = (u16*)(ws + (64ull << 20));            // 16 MiB (q -> ctx in place)
    u16* wq_bf  = (u16*)(ws + (80ull << 20));
    u16* wk_bf  = wq_bf + 1048576;
    u16* wv_bf  = wk_bf + 1048576;
    u16* wo_bf  = wv_bf + 1048576;
    u16* wp_bf  = wo_bf + 1048576;                       // 1310720
    u16* te_bf  = wp_bf + 1310720;                       // 256000
    u16* sv_bf  = enc_bf;                                // semvec reuses enc region
    u16* v_bf   = (u16*)d_out;                           // 32 MiB scratch in out1 (dead before final proj)

    const float qscale = 0.08838834764831845f;           // DH^-0.5
    dim3 blk(256);

    // bf16 plane conversions
    conv_k<<<dim3(16384), blk, 0, stream>>>(enc,   enc_bf, 16777216);
    conv_k<<<dim3(1024),  blk, 0, stream>>>(wq,    wq_bf,  1048576);
    conv_k<<<dim3(1024),  blk, 0, stream>>>(wk,    wk_bf,  1048576);
    conv_k<<<dim3(1024),  blk, 0, stream>>>(wv,    wv_bf,  1048576);
    conv_k<<<dim3(1024),  blk, 0, stream>>>(wo,    wo_bf,  1048576);
    conv_k<<<dim3(1280),  blk, 0, stream>>>(wproj, wp_bf,  1310720);
    conv_k<<<dim3(250),   blk, 0, stream>>>(temb,  te_bf,  256000);

    // k = enc @ wk^T + bk            (bf16 out)
    mm_k<AM_PLAIN, OM_BF16><<<dim3(1024), blk, 0, stream>>>(
        enc_bf, wk_bf, bk, k_bf, nullptr, nullptr, B_ * S_, D_, nullptr, nullptr, 1.0f);
    // v = enc @ wv^T + bv            (bf16 out, in d_out)
    mm_k<AM_PLAIN, OM_BF16><<<dim3(1024), blk, 0, stream>>>(
        enc_bf, wv_bf, bv, v_bf, nullptr, nullptr, B_ * S_, D_, nullptr, nullptr, 1.0f);
    // q = (gather(enc) @ wq^T + bq) * scale
    mm_k<AM_GATHER, OM_BF16><<<dim3(512), blk, 0, stream>>>(
        nullptr, wq_bf, bq, q_bf, nullptr, nullptr, B_ * L_, D_, to_sem, enc_bf, qscale);
    // sparse masked attention (ctx overwrites q)
    attn_k<<<dim3(B_ * L_), blk, 0, stream>>>(k_bf, v_bf, semsyn, to_sem, q_bf);
    // semvec = ctx @ wo^T + bo
    mm_k<AM_PLAIN, OM_BF16><<<dim3(512), blk, 0, stream>>>(
        q_bf, wo_bf, bo, sv_bf, nullptr, nullptr, B_ * L_, D_, nullptr, nullptr, 1.0f);
    // embedding = [semvec | temb[tstype]] @ wproj^T + bproj -> out1, out2 rows 1..L
    mm_k<AM_CONCAT, OM_FINAL><<<dim3(512), blk, 0, stream>>>(
        sv_bf, wp_bf, bproj, nullptr, out1, out2, B_ * L_, KP_, tstype, te_bf, 1.0f);
    // out2 row 0 = bias_root
    root_k<<<dim3((B_ * D_) / 256), blk, 0, stream>>>(broot, out2);
}

// Round 3
// 270.664 us; speedup vs baseline: 6.2805x; 1.0533x over previous
//
#include <hip/hip_runtime.h>

typedef unsigned short u16;
typedef unsigned int   u32;
typedef __bf16 bf16x8 __attribute__((ext_vector_type(8)));
typedef float  f32x4  __attribute__((ext_vector_type(4)));

#define B_  16
#define S_  1024
#define L_  512
#define D_  1024
#define H_  8
#define WD_ 256
#define KP_ (D_ + WD_)

__device__ __forceinline__ u16 f2bf(float f) {
    u32 u = __float_as_uint(f);
    return (u16)((u + 0x7FFFu + ((u >> 16) & 1u)) >> 16);
}
__device__ __forceinline__ float bf2f(u16 h) {
    return __uint_as_float(((u32)h) << 16);
}
__device__ __forceinline__ void gload16(const void* g, void* l) {
    __builtin_amdgcn_global_load_lds(
        (const __attribute__((address_space(1))) u32*)(unsigned long long)(g),
        (__attribute__((address_space(3))) u32*)(unsigned long long)(l),
        16, 0, 0);
}

// ---------- conversions ----------
__global__ __launch_bounds__(256) void conv_s(const float* __restrict__ x,
                                              u16* __restrict__ y, int n, float s) {
    const int i = (blockIdx.x * 256 + threadIdx.x) * 4;
    if (i < n) {
        const float4 v = *(const float4*)(x + i);
        ushort4 o;
        o.x = f2bf(v.x * s); o.y = f2bf(v.y * s); o.z = f2bf(v.z * s); o.w = f2bf(v.w * s);
        *(ushort4*)(y + i) = o;
    }
}

// wot[k*1024+t] = bf16(wo[t*1024+k])  (1024x1024 transpose)
__global__ __launch_bounds__(256) void convT_k(const float* __restrict__ x, u16* __restrict__ y) {
    __shared__ float tile[64][65];
    const int t0 = (blockIdx.x & 15) * 64;
    const int k0 = (blockIdx.x >> 4) * 64;
    const int tr = threadIdx.x >> 4;
    const int tc = threadIdx.x & 15;
    #pragma unroll
    for (int i = 0; i < 4; ++i) {
        const int r = tr + i * 16;
        const float4 v = *(const float4*)(x + (size_t)(t0 + r) * 1024 + k0 + tc * 4);
        tile[r][tc * 4 + 0] = v.x; tile[r][tc * 4 + 1] = v.y;
        tile[r][tc * 4 + 2] = v.z; tile[r][tc * 4 + 3] = v.w;
    }
    __syncthreads();
    #pragma unroll
    for (int i = 0; i < 4; ++i) {
        const int r = tr + i * 16;
        ushort4 o;
        o.x = f2bf(tile[tc * 4 + 0][r]);
        o.y = f2bf(tile[tc * 4 + 1][r]);
        o.z = f2bf(tile[tc * 4 + 2][r]);
        o.w = f2bf(tile[tc * 4 + 3][r]);
        *(ushort4*)(y + (size_t)(k0 + r) * 1024 + t0 + tc * 4) = o;
    }
}

// split wproj [1024 x 1280] -> wp1 (cols 0..1023, stride 1024) and wfin tail (cols 1024.., stride 1280)
__global__ __launch_bounds__(256) void convP_k(const float* __restrict__ x,
                                               u16* __restrict__ wp1, u16* __restrict__ wfin) {
    const int i = (blockIdx.x * 256 + threadIdx.x) * 4;
    if (i >= 1024 * 1280) return;
    const int n = i / 1280, c = i % 1280;
    const float4 v = *(const float4*)(x + i);
    ushort4 o;
    o.x = f2bf(v.x); o.y = f2bf(v.y); o.z = f2bf(v.z); o.w = f2bf(v.w);
    if (c < 1024) *(ushort4*)(wp1 + (size_t)n * 1024 + c) = o;
    else          *(ushort4*)(wfin + (size_t)n * 1280 + c) = o;
}

__global__ __launch_bounds__(256) void bfuse_k(const float* __restrict__ bk,
                                               const float* __restrict__ bv,
                                               const float* __restrict__ bq, float qs,
                                               float* __restrict__ bkvq) {
    const int i = blockIdx.x * 256 + threadIdx.x;
    if (i < 3072)
        bkvq[i] = (i < 1024) ? bk[i] : (i < 2048 ? bv[i - 1024] : bq[i - 2048] * qs);
}

// beff[n] = bproj[n] + sum_t wproj[n,t]*bo[t]  (t<1024)
__global__ __launch_bounds__(256) void beff_k(const float* __restrict__ wproj,
                                              const float* __restrict__ bo,
                                              const float* __restrict__ bproj,
                                              float* __restrict__ beff) {
    const int w = threadIdx.x >> 6, lane = threadIdx.x & 63;
    const int n = blockIdx.x * 4 + w;
    const float* row = wproj + (size_t)n * 1280;
    float s = 0.f;
    for (int t = lane; t < 1024; t += 64) s += row[t] * bo[t];
    #pragma unroll
    for (int off = 32; off > 0; off >>= 1) s += __shfl_down(s, off);
    if (lane == 0) beff[n] = bproj[n] + s;
}

// ---------- 8-phase deep-pipelined 256x256 GEMM (KVQ), BK=32, 4-slot LDS ring ----------
// Y = A @ W^T + bias ; A [M x K] bf16, W [N x K] bf16, N = ntn*256.
// Output routed per 1024-col plane: plane 0 -> o0, 1 -> o1, 2 -> o2 (each [M x 1024] bf16).
template <int NT>
__global__ __launch_bounds__(512, 2) void mm8_k(
    const u16* __restrict__ A, const u16* __restrict__ W,
    const float* __restrict__ bias,
    u16* __restrict__ o0, u16* __restrict__ o1, u16* __restrict__ o2,
    int K, int ntn)
{
    __shared__ alignas(16) u16 lds[65536];   // 4 slots x (A 8192 + B 8192) u16
    const int tid  = threadIdx.x;
    const int w    = tid >> 6;
    const int lane = tid & 63;
    const int l15  = lane & 15;
    const int lk   = lane >> 4;
    const int wr   = w >> 2;     // 0..1
    const int wc   = w & 3;      // 0..3

    const int nwg = gridDim.x;
    const int bid = blockIdx.x;
    const int e   = (bid & 7) * (nwg >> 3) + (bid >> 3);
    const int bm0 = (e / ntn) * 256;
    const int bn0 = (e % ntn) * 256;

    // staging: wave w stages A rows [w*32, w*32+32) (2 insts) and same B rows.
    const int l2   = lane >> 2;
    const int c_st = lane & 3;
    size_t asrc[2], bsrc[2];
    #pragma unroll
    for (int i = 0; i < 2; ++i) {
        const int r = (w * 2 + i) * 16 + l2;
        const int g = c_st ^ (r & 3) ^ ((r >> 2) & 3);
        asrc[i] = (size_t)(bm0 + r) * K + g * 8;
        bsrc[i] = (size_t)(bn0 + r) * K + g * 8;
    }
    const int dstA = (w * 2) * 512;   // u16 elems within slot

#define STAGE_A(t) { u16* d = lds + ((t) & 3) * 16384 + dstA;          \
    gload16(A + asrc[0] + (size_t)(t) * 32, d);                        \
    gload16(A + asrc[1] + (size_t)(t) * 32, d + 512); }
#define STAGE_B(t) { u16* d = lds + ((t) & 3) * 16384 + 8192 + dstA;   \
    gload16(W + bsrc[0] + (size_t)(t) * 32, d);                        \
    gload16(W + bsrc[1] + (size_t)(t) * 32, d + 512); }

    // reader offsets (both-sides swizzle: lane-static)
    const int c_rd = lk ^ (l15 & 3) ^ ((l15 >> 2) & 3);
    const int aoff = (wr * 128 + l15) * 32 + c_rd * 8;   // + mf*512
    const int boff = (wc * 64 + l15) * 32 + c_rd * 8;    // + nf*512

    f32x4 acc[8][4] = {};

    STAGE_A(0); STAGE_B(0);
    STAGE_A(1); STAGE_B(1);
    STAGE_A(2); STAGE_B(2);
    asm volatile("s_waitcnt vmcnt(8)" ::: "memory");
    __builtin_amdgcn_sched_barrier(0);
    __builtin_amdgcn_s_barrier();

    for (int t = 0; t < NT; ++t) {
        const u16* sa = lds + (t & 3) * 16384 + aoff;
        const u16* sb = lds + (t & 3) * 16384 + 8192 + boff;
        bf16x8 af[4], bfr[4];
        // ---- phase a: C-halves mf 0..3 ----
        #pragma unroll
        for (int nf = 0; nf < 4; ++nf) bfr[nf] = *(const bf16x8*)(sb + nf * 512);
        #pragma unroll
        for (int mf = 0; mf < 4; ++mf) af[mf] = *(const bf16x8*)(sa + mf * 512);
        if (t + 3 < NT) STAGE_A(t + 3);
        __builtin_amdgcn_s_barrier();
        __builtin_amdgcn_s_setprio(1);
        #pragma unroll
        for (int mf = 0; mf < 4; ++mf)
            #pragma unroll
            for (int nf = 0; nf < 4; ++nf)
                acc[mf][nf] = __builtin_amdgcn_mfma_f32_16x16x32_bf16(af[mf], bfr[nf], acc[mf][nf], 0, 0, 0);
        __builtin_amdgcn_s_setprio(0);
        __builtin_amdgcn_s_barrier();
        // ---- phase b: mf 4..7 ----
        #pragma unroll
        for (int mf = 0; mf < 4; ++mf) af[mf] = *(const bf16x8*)(sa + (mf + 4) * 512);
        if (t + 3 < NT) STAGE_B(t + 3);
        __builtin_amdgcn_s_barrier();
        __builtin_amdgcn_s_setprio(1);
        #pragma unroll
        for (int mf = 0; mf < 4; ++mf)
            #pragma unroll
            for (int nf = 0; nf < 4; ++nf)
                acc[mf + 4][nf] = __builtin_amdgcn_mfma_f32_16x16x32_bf16(af[mf], bfr[nf], acc[mf + 4][nf], 0, 0, 0);
        __builtin_amdgcn_s_setprio(0);
        if (t < NT - 3)      { asm volatile("s_waitcnt vmcnt(8)" ::: "memory"); }
        else if (t == NT - 3){ asm volatile("s_waitcnt vmcnt(4)" ::: "memory"); }
        else if (t == NT - 2){ asm volatile("s_waitcnt vmcnt(0)" ::: "memory"); }
        __builtin_amdgcn_sched_barrier(0);
        __builtin_amdgcn_s_barrier();
    }
#undef STAGE_A
#undef STAGE_B

    // epilogue: route by 1024-col plane (256-tile never straddles planes)
    const int plane = bn0 >> 10;
    u16* outp = plane == 0 ? o0 : (plane == 1 ? o1 : o2);
    const int cip0 = (bn0 & 1023) + wc * 64 + l15;
    const int colg = bn0 + wc * 64 + l15;
    float bsv[4];
    #pragma unroll
    for (int nf = 0; nf < 4; ++nf) bsv[nf] = bias[colg + nf * 16];
    #pragma unroll
    for (int mf = 0; mf < 8; ++mf) {
        const int mrow = bm0 + wr * 128 + mf * 16 + lk * 4;
        #pragma unroll
        for (int nf = 0; nf < 4; ++nf) {
            const int cip = cip0 + nf * 16;
            #pragma unroll
            for (int r = 0; r < 4; ++r)
                outp[(size_t)(mrow + r) * 1024 + cip] = f2bf(acc[mf][nf][r] + bsv[nf]);
        }
    }
}

// ---------- proven 128x128 GEMM (Weff + final) ----------
#define BM 128
#define BN 128
#define BK 32
#define AM_PLAIN  0
#define AM_CONCAT 2
#define OM_BF16   0
#define OM_FINAL  1

template <int AMODE, int OMODE>
__global__ __launch_bounds__(256) void mm_k(
    const u16* __restrict__ A, const u16* __restrict__ W,
    const float* __restrict__ bias,
    u16* __restrict__ Ybf, float* __restrict__ Yf, float* __restrict__ Y2,
    int M, int K, int ostride,
    const int* __restrict__ gidx, const u16* __restrict__ aux)
{
    constexpr int N = 1024;
    __shared__ alignas(16) u16 As[BM * BK];
    __shared__ alignas(16) u16 Bs[BN * BK];

    const int tid  = threadIdx.x;
    const int wid  = tid >> 6;
    const int lane = tid & 63;

    const int nwg = gridDim.x;
    const int bid = blockIdx.x;
    const int e   = (bid & 7) * (nwg >> 3) + (bid >> 3);
    const int bm0 = (e >> 3) * BM;
    const int bn0 = (e & 7) * BN;

    const int srow = lane >> 2;
    const int kcs  = ((lane & 3) ^ ((lane >> 2) & 3)) * 8;
    const int rA0  = 32 * wid + srow;
    const int rA1  = rA0 + 16;

    long gr0, gr1;
    if (AMODE == AM_PLAIN) {
        gr0 = (long)(bm0 + rA0) * K;
        gr1 = (long)(bm0 + rA1) * K;
    } else {
        gr0 = (long)(bm0 + rA0) * D_;
        gr1 = (long)(bm0 + rA1) * D_;
    }
    long tr0 = 0, tr1 = 0;
    if (AMODE == AM_CONCAT) {
        tr0 = (long)gidx[bm0 + rA0] * WD_;
        tr1 = (long)gidx[bm0 + rA1] * WD_;
    }
    const long wr0 = (long)(bn0 + rA0) * K;
    const long wr1 = (long)(bn0 + rA1) * K;

    u16* aB0 = As + (2 * wid) * 512;
    u16* aB1 = As + (2 * wid + 1) * 512;
    u16* bB0 = Bs + (2 * wid) * 512;
    u16* bB1 = Bs + (2 * wid + 1) * 512;

    f32x4 acc[4][4] = {};

    const int moff = (wid >> 1) * 64;
    const int noff = (wid & 1) * 64;
    const int l15  = lane & 15;
    const int lk   = lane >> 4;
    const int rdk  = (lk ^ (l15 & 3)) * 8;

    for (int k0 = 0; k0 < K; k0 += BK) {
        const u16 *a0, *a1;
        if (AMODE == AM_CONCAT && k0 >= D_) {
            a0 = aux + tr0 + (k0 - D_) + kcs;
            a1 = aux + tr1 + (k0 - D_) + kcs;
        } else {
            a0 = A + gr0 + k0 + kcs;
            a1 = A + gr1 + k0 + kcs;
        }
        gload16(a0, aB0);
        gload16(a1, aB1);
        gload16(W + wr0 + k0 + kcs, bB0);
        gload16(W + wr1 + k0 + kcs, bB1);
        __syncthreads();

        bf16x8 af[4], bfr[4];
        #pragma unroll
        for (int i = 0; i < 4; ++i)
            af[i] = *(const bf16x8*)(As + (moff + i * 16 + l15) * 32 + rdk);
        #pragma unroll
        for (int j = 0; j < 4; ++j)
            bfr[j] = *(const bf16x8*)(Bs + (noff + j * 16 + l15) * 32 + rdk);
        #pragma unroll
        for (int i = 0; i < 4; ++i)
            #pragma unroll
            for (int j = 0; j < 4; ++j)
                acc[i][j] = __builtin_amdgcn_mfma_f32_16x16x32_bf16(af[i], bfr[j], acc[i][j], 0, 0, 0);
        __syncthreads();
    }

    #pragma unroll
    for (int j = 0; j < 4; ++j) {
        const int col = bn0 + noff + j * 16 + l15;
        const float bj = bias ? bias[col] : 0.f;
        #pragma unroll
        for (int i = 0; i < 4; ++i) {
            const int mrow = bm0 + moff + i * 16 + lk * 4;
            #pragma unroll
            for (int r = 0; r < 4; ++r) {
                const float val = acc[i][j][r] + bj;
                const long m = mrow + r;
                if (OMODE == OM_BF16) {
                    Ybf[m * (long)ostride + col] = f2bf(val);
                } else {
                    Yf[m * (long)N + col] = val;
                    const long bb = m >> 9, ll = m & 511;
                    Y2[((bb * (L_ + 1)) + ll + 1) * (long)D_ + col] = val;
                }
            }
        }
    }
}

// ---------- sparse masked attention ----------
__global__ __launch_bounds__(256) void attn_k(
    const u16* __restrict__ kb, const u16* __restrict__ vb,
    const int* __restrict__ sem_syn, const int* __restrict__ to_sem,
    const u16* __restrict__ qf, u16* __restrict__ ctx)
{
    __shared__ int   list[S_];
    __shared__ float sc[H_][S_];
    __shared__ int   pcnt[256];

    const int bl  = blockIdx.x;
    const int b   = bl >> 9;
    const int l   = bl & 511;
    const int tid = threadIdx.x;

    const int tosem = to_sem[bl];
    const ushort4 qu = *(const ushort4*)(qf + ((size_t)b * S_ + tosem) * D_ + tid * 4);
    const float4 qv = make_float4(bf2f(qu.x), bf2f(qu.y), bf2f(qu.z), bf2f(qu.w));

    bool al[4];
    int  cl = 0;
    #pragma unroll
    for (int j = 0; j < 4; ++j) {
        const int s = tid * 4 + j;
        const int a = sem_syn[b * S_ + s];
        al[j] = (a == l + 1) || (s == tosem);
        cl += al[j] ? 1 : 0;
    }
    pcnt[tid] = cl;
    __syncthreads();
    for (int off = 1; off < 256; off <<= 1) {
        const int x = (tid >= off) ? pcnt[tid - off] : 0;
        __syncthreads();
        pcnt[tid] += x;
        __syncthreads();
    }
    int pos = pcnt[tid] - cl;
    #pragma unroll
    for (int j = 0; j < 4; ++j)
        if (al[j]) list[pos++] = tid * 4 + j;
    const int n = pcnt[255];
    __syncthreads();

    const int g = tid >> 5;
    const int lane = tid & 31;
    for (int i = 0; i < n; ++i) {
        const u16* krow = kb + ((size_t)b * S_ + list[i]) * D_;
        const ushort4 ku = *(const ushort4*)(krow + tid * 4);
        float p = bf2f(ku.x) * qv.x + bf2f(ku.y) * qv.y + bf2f(ku.z) * qv.z + bf2f(ku.w) * qv.w;
        #pragma unroll
        for (int off = 16; off > 0; off >>= 1) p += __shfl_down(p, off, 32);
        if (lane == 0) sc[g][i] = p;
    }
    __syncthreads();

    float mx = -3.0e38f;
    for (int i = lane; i < n; i += 32) mx = fmaxf(mx, sc[g][i]);
    #pragma unroll
    for (int off = 16; off > 0; off >>= 1) mx = fmaxf(mx, __shfl_xor(mx, off, 32));
    float sum = 0.f;
    for (int i = lane; i < n; i += 32) {
        const float e = expf(sc[g][i] - mx);
        sc[g][i] = e;
        sum += e;
    }
    #pragma unroll
    for (int off = 16; off > 0; off >>= 1) sum += __shfl_xor(sum, off, 32);
    const float inv = 1.0f / sum;
    __syncthreads();

    float4 a4 = make_float4(0.f, 0.f, 0.f, 0.f);
    for (int i = 0; i < n; ++i) {
        const float wgt = sc[g][i] * inv;
        const u16* vrow = vb + ((size_t)b * S_ + list[i]) * D_;
        const ushort4 vu = *(const ushort4*)(vrow + tid * 4);
        a4.x = fmaf(wgt, bf2f(vu.x), a4.x);
        a4.y = fmaf(wgt, bf2f(vu.y), a4.y);
        a4.z = fmaf(wgt, bf2f(vu.z), a4.z);
        a4.w = fmaf(wgt, bf2f(vu.w), a4.w);
    }
    ushort4 o;
    o.x = f2bf(a4.x); o.y = f2bf(a4.y); o.z = f2bf(a4.z); o.w = f2bf(a4.w);
    *(ushort4*)(ctx + (size_t)bl * D_ + tid * 4) = o;
}

__global__ __launch_bounds__(256) void root_k(
    const float* __restrict__ broot, float* __restrict__ out2)
{
    const int i = blockIdx.x * 256 + threadIdx.x;
    const int b = i >> 10, d = i & 1023;
    out2[(size_t)b * (L_ + 1) * D_ + d] = broot[d];
}

extern "C" void kernel_launch(void* const* d_in, const int* in_sizes, int n_in,
                              void* d_out, int out_size, void* d_ws, size_t ws_size,
                              hipStream_t stream)
{
    const float* enc    = (const float*)d_in[0];
    const int*   to_sem = (const int*)  d_in[1];
    const int*   tstype = (const int*)  d_in[2];
    const int*   semsyn = (const int*)  d_in[3];
    const float* wq = (const float*)d_in[4];
    const float* bq = (const float*)d_in[5];
    const float* wk = (const float*)d_in[6];
    const float* bk = (const float*)d_in[7];
    const float* wv = (const float*)d_in[8];
    const float* bv = (const float*)d_in[9];
    const float* wo = (const float*)d_in[10];
    const float* bo = (const float*)d_in[11];
    const float* temb  = (const float*)d_in[12];
    const float* wproj = (const float*)d_in[13];
    const float* bproj = (const float*)d_in[14];
    const float* broot = (const float*)d_in[15];

    float* out1 = (float*)d_out;
    float* out2 = out1 + (size_t)B_ * L_ * D_;

    unsigned char* ws = (unsigned char*)d_ws;
    u16*   enc_bf = (u16*)(ws);
    u16*   k_bf   = (u16*)(ws + (32ull << 20));
    u16*   wkvq   = (u16*)(ws + (64ull << 20));          // [3072 x 1024]
    u16*   wot    = (u16*)(ws + (70ull << 20));          // wo^T bf16
    u16*   wp1    = (u16*)(ws + (72ull << 20));          // wproj cols 0..1023
    u16*   wfin   = (u16*)(ws + (74ull << 20));          // [1024 x 1280]
    float* beff   = (float*)(ws + (77ull << 20));
    float* bkvq   = (float*)(ws + (77ull << 20) + 8192);
    u16*   ctx_bf = (u16*)(ws + (78ull << 20));          // [8192 x 1024]
    u16*   te_bf  = (u16*)(ws + (94ull << 20));          // [1000 x 256]

    u16* v_bf = (u16*)d_out;                                   // 32MiB in out1 area
    u16* q_bf = (u16*)((unsigned char*)d_out + (32ull << 20)); // 32MiB in out2 area

    const float qscale = 0.08838834764831845f;   // DH^-0.5
    dim3 blk(256);

    // conversions / weight prep
    conv_s<<<dim3(16384), blk, 0, stream>>>(enc, enc_bf, 16777216, 1.0f);
    conv_s<<<dim3(1024),  blk, 0, stream>>>(wk, wkvq,               1048576, 1.0f);
    conv_s<<<dim3(1024),  blk, 0, stream>>>(wv, wkvq + 1048576,     1048576, 1.0f);
    conv_s<<<dim3(1024),  blk, 0, stream>>>(wq, wkvq + 2097152,     1048576, qscale);
    bfuse_k<<<dim3(12),   blk, 0, stream>>>(bk, bv, bq, qscale, bkvq);
    convT_k<<<dim3(256),  blk, 0, stream>>>(wo, wot);
    convP_k<<<dim3(1280), blk, 0, stream>>>(wproj, wp1, wfin);
    conv_s<<<dim3(250),   blk, 0, stream>>>(temb, te_bf, 256000, 1.0f);
    beff_k<<<dim3(256),   blk, 0, stream>>>(wproj, bo, bproj, beff);

    // fused K|V|Q GEMM: [16384 x 1024] @ [3072 x 1024]^T
    mm8_k<32><<<dim3(768), dim3(512), 0, stream>>>(
        enc_bf, wkvq, bkvq, k_bf, v_bf, q_bf, 1024, 12);

    // Weff = Wp1 @ wo  -> wfin cols 0..1023 (stride 1280), no bias
    mm_k<AM_PLAIN, OM_BF16><<<dim3(64), blk, 0, stream>>>(
        wp1, wot, nullptr, wfin, nullptr, nullptr, 1024, 1024, 1280, nullptr, nullptr);

    // sparse masked attention (q gathered via to_sem)
    attn_k<<<dim3(B_ * L_), blk, 0, stream>>>(k_bf, v_bf, semsyn, to_sem, q_bf, ctx_bf);

    // final: [ctx | temb[tstype]] @ wfin^T + beff -> out1, out2 rows 1..L
    mm_k<AM_CONCAT, OM_FINAL><<<dim3(512), blk, 0, stream>>>(
        ctx_bf, wfin, beff, nullptr, out1, out2, B_ * L_, KP_, 1024, tstype, te_bf);

    root_k<<<dim3((B_ * D_) / 256), blk, 0, stream>>>(broot, out2);
}